// Round 14
// baseline (101.753 us; speedup 1.0000x reference)
//
#include <hip/hip_runtime.h>

// AttentionBlock: B=8, C=256, S=2048, H=4, DK=64
// k_prep (transpose+cast x->xt [chunk-swizzled]; wp,wo chunk-swizzled casts)
// -> k_qkv (LDS-staged A/B, LDS-repacked coalesced outputs)
// -> k_attn (4 waves x 16 q, TRIPLE-buffered KV, counted vmcnt(8) + raw s_barrier;
//            res written chunk-swizzled)
// -> k_out (LDS-staged res/wo/x, fp32 repack, full-line coalesced stores)
// fp16 storage, fp32 MFMA accum. Softmax: constant-shift exp2 (scale*log2e in Q,
// shift in MFMA C-init), raw v_exp_f32, denominator via ones-row MFMA (K=32 PV).
// Swizzle convention (rows of 256 f16 = 32 16B-chunks): chunk ch of row r stored
// at ch ^ (r&7). Same involution on write and read.

typedef _Float16 f16;
typedef __attribute__((ext_vector_type(4))) float f32x4;
typedef __attribute__((ext_vector_type(8))) _Float16 h8;
typedef __attribute__((ext_vector_type(4))) _Float16 h4;
typedef __attribute__((ext_vector_type(2))) __fp16 fp16x2;
typedef __attribute__((ext_vector_type(4))) __fp16 fp16x4;
typedef __attribute__((ext_vector_type(8))) __fp16 fp16x8;

#define SS 2048
#define CC 256
#define BB 8
#define HH 4
#define DK 64
#define O3 768
#define NT64 32  // 32 tiles of 64 keys; tile = 4096 f16 (8KB) each for K and V
#define C1F 0.1803368801111204f   // 0.125 * log2(e)
#define C2L2 11.541560327111707f  // 8 * log2(e)

#define MFMA32(a, b, c) __builtin_amdgcn_mfma_f32_16x16x32_f16(a, b, c, 0, 0, 0)

#if __has_builtin(__builtin_amdgcn_exp2f)
#define EXP2(x) __builtin_amdgcn_exp2f(x)  // raw v_exp_f32 (args in [-40,-3]: safe)
#else
#define EXP2(x) exp2f(x)
#endif

__device__ __forceinline__ void async_ld16(const f16* g, f16* lds) {
  __builtin_amdgcn_global_load_lds(
      (const __attribute__((address_space(1))) unsigned int*)g,
      (__attribute__((address_space(3))) unsigned int*)lds, 16, 0, 0);
}

// ---------------- prep ----------------
// z<8 : xt[b][s][swizzled c] = (f16) x[b][c][s]
// z==8: weight casts; wp AND wo rows chunk-swizzled
__global__ __launch_bounds__(256) void k_prep(const float* __restrict__ x,
                                              f16* __restrict__ xt,
                                              const float* __restrict__ w_proj,
                                              const float* __restrict__ w_out,
                                              f16* __restrict__ wp, f16* __restrict__ wo) {
  if (blockIdx.z == 8) {
    int slice = blockIdx.y * 32 + blockIdx.x;  // 0..127
    int i0 = slice * 2048 + threadIdx.x * 8;
    const float* src;
    f16* dst;
    if (i0 < O3 * CC) {
      src = w_proj + i0;
      int row = i0 >> 8, ch = (i0 & 255) >> 3;
      dst = wp + row * 256 + ((ch ^ (row & 7)) << 3);
    } else {
      int j = i0 - O3 * CC;
      src = w_out + j;
      int row = j >> 8, ch = (j & 255) >> 3;
      dst = wo + row * 256 + ((ch ^ (row & 7)) << 3);
    }
    float4 a = *(const float4*)src;
    float4 b = *(const float4*)(src + 4);
    h8 v = {(f16)a.x, (f16)a.y, (f16)a.z, (f16)a.w,
            (f16)b.x, (f16)b.y, (f16)b.z, (f16)b.w};
    *(h8*)dst = v;
    return;
  }
  __shared__ float tile[64][65];
  int b = blockIdx.z, c0 = blockIdx.y * 64, s0 = blockIdx.x * 64;
  int t = threadIdx.x;
#pragma unroll
  for (int it = 0; it < 16; ++it) {
    int idx = it * 256 + t;
    int cl = idx >> 6, sl = idx & 63;
    tile[cl][sl] = x[(size_t)(b * CC + c0 + cl) * SS + s0 + sl];
  }
  __syncthreads();
#pragma unroll
  for (int cid = t; cid < 512; cid += 256) {
    int sl = cid >> 3, chl = cid & 7;
    int s = s0 + sl;
    int gch = (c0 >> 3) + chl;
    h8 v;
#pragma unroll
    for (int e = 0; e < 8; ++e) v[e] = (f16)tile[chl * 8 + e][sl];
    *(h8*)(xt + (size_t)(b * SS + s) * CC + ((gch ^ (s & 7)) << 3)) = v;
  }
}

// ---------------- QKV GEMM (LDS-staged, coalesced in AND out) ----------------
__global__ __launch_bounds__(256) void k_qkv(const f16* __restrict__ xt,
                                             const f16* __restrict__ wp,
                                             const float* __restrict__ bp,
                                             f16* __restrict__ qh, f16* __restrict__ ksw,
                                             f16* __restrict__ vsw) {
  __shared__ f16 As[16384];  // 64 x 256 (32KB)
  __shared__ f16 Bs[16384];  // 64 x 256 (32KB)
  __shared__ f16 Ot[4096];   // 8KB out staging
  int b = blockIdx.z;
  int oti = blockIdx.y, o0 = oti * 64;
  int s0 = blockIdx.x * 64;
  int w = threadIdx.x >> 6, l = threadIdx.x & 63;
  int lr = l & 15, lg = l >> 4;

  const f16* Ag = xt + ((size_t)b * SS + s0) * CC;  // 32KB contiguous
  const f16* Bg = wp + (size_t)o0 * CC;
#pragma unroll
  for (int i = 0; i < 8; ++i) {
    int off = w * 4096 + i * 512;
    async_ld16(Ag + off + l * 8, &As[off]);
    async_ld16(Bg + off + l * 8, &Bs[off]);
  }
  asm volatile("s_waitcnt vmcnt(0)" ::: "memory");
  __syncthreads();

  f32x4 acc[4] = {};
#pragma unroll
  for (int kk = 0; kk < CC; kk += 32) {
    int chs = (((kk >> 3) + lg) ^ (lr & 7)) << 3;
    h8 af = *(const h8*)&As[(w * 16 + lr) * 256 + chs];
#pragma unroll
    for (int n = 0; n < 4; ++n) {
      h8 bf = *(const h8*)&Bs[(n * 16 + lr) * 256 + chs];
      acc[n] = MFMA32(af, bf, acc[n]);
    }
  }

  int seg = oti % 3;  // 0=q 1=k 2=v
  int h = oti / 3;
  int bh = b * HH + h;
  float scl = (seg == 0) ? C1F : 1.0f;
#pragma unroll
  for (int n = 0; n < 4; ++n) {
    float bb = bp[o0 + n * 16 + lr];
#pragma unroll
    for (int r = 0; r < 4; ++r) acc[n][r] = (acc[n][r] + bb) * scl;
  }

  // repack D into Ot at target layout (wave-disjoint addresses)
  if (seg == 2) {
#pragma unroll
    for (int n = 0; n < 4; ++n) {
      int d = n * 16 + lr;
#pragma unroll
      for (int r = 0; r < 4; ++r) {
        int sl = w * 16 + lg * 4 + r;
        int kl = sl & 31;
        int ps = ((kl & 15) >> 2) ^ ((d >> 1) & 3);
        Ot[(sl >> 5) * 2048 + d * 32 + ps * 8 + ((kl >> 4) << 2) + (kl & 3)] =
            (f16)acc[n][r];
      }
    }
  } else if (seg == 1) {
#pragma unroll
    for (int n = 0; n < 4; ++n) {
      int d = n * 16 + lr;
#pragma unroll
      for (int r = 0; r < 4; ++r) {
        int sl = w * 16 + lg * 4 + r;
        int kl = sl & 31;
        Ot[(sl >> 5) * 2048 + kl * 64 + (((d >> 3) ^ (kl & 7)) << 3) + (d & 7)] =
            (f16)acc[n][r];
      }
    }
  } else {
#pragma unroll
    for (int n = 0; n < 4; ++n)
#pragma unroll
      for (int r = 0; r < 4; ++r)
        Ot[(w * 16 + lg * 4 + r) * 64 + n * 16 + lr] = (f16)acc[n][r];
  }
  __syncthreads();

  int t = threadIdx.x;
  f16* dst;
  if (seg == 0)
    dst = qh + ((size_t)bh * SS + s0) * DK;
  else if (seg == 1)
    dst = ksw + ((size_t)bh * NT64 + (s0 >> 6)) * 4096;
  else
    dst = vsw + ((size_t)bh * NT64 + (s0 >> 6)) * 4096;
  *(int4*)(dst + t * 16) = *(const int4*)&Ot[t * 16];
  *(int4*)(dst + t * 16 + 8) = *(const int4*)&Ot[t * 16 + 8];
}

// ---------------- attention: 4 waves x 16 q, TRIPLE-buffered pipeline ----------------
// 1024 blocks; 48KB LDS -> 3 blocks/CU = 12 waves/CU. Per wave per tile: 4 loads.
// Prologue stages tiles 0,1,2 (12 outstanding). Loop t: vmcnt(8) (tile t's 4
// retired; t+1,t+2 in flight) -> s_barrier -> compute buf[t%3] -> s_barrier ->
// STAGE(t%3, t+3). Issue-to-wait slack = 2 full iterations (~HBM latency covered).
__global__ __launch_bounds__(256) void k_attn(const f16* __restrict__ qh,
                                              const f16* __restrict__ ksw,
                                              const f16* __restrict__ vsw,
                                              f16* __restrict__ res) {
  __shared__ f16 kbuf[3][4096];
  __shared__ f16 vbuf[3][4096];
  int id = blockIdx.x;
  int xcd = id & 7, slot = id >> 3;  // 128 slots per XCD
  int bh = xcd * 4 + (slot >> 5);    // 4 heads per XCD -> K/V L2-resident
  int qt = slot & 31;
  int w = threadIdx.x >> 6, l = threadIdx.x & 63;
  int q0 = qt * 64 + w * 16;
  int lr = l & 15, lg = l >> 4;

  const f16* qp = qh + (size_t)(bh * SS + q0 + lr) * DK;
  h8 qf0 = *(const h8*)(qp + lg * 8);
  h8 qf1 = *(const h8*)(qp + 32 + lg * 8);

  const f16* kg = ksw + (size_t)bh * (SS * DK);
  const f16* vg = vsw + (size_t)bh * (SS * DK);

#define STAGE(bufi, tile)                                           \
  {                                                                 \
    const f16* kq = kg + (size_t)(tile) * 4096 + w * 1024 + l * 8;  \
    const f16* vq = vg + (size_t)(tile) * 4096 + w * 1024 + l * 8;  \
    f16* kd = &kbuf[bufi][w * 1024];                                \
    f16* vd = &vbuf[bufi][w * 1024];                                \
    async_ld16(kq, kd);                                             \
    async_ld16(kq + 512, kd + 512);                                 \
    async_ld16(vq, vd);                                             \
    async_ld16(vq + 512, vd + 512);                                 \
  }

  int swk = (lr & 7) << 3;
  int ek[2][2];
#pragma unroll
  for (int kb = 0; kb < 2; ++kb)
#pragma unroll
    for (int ch = 0; ch < 2; ++ch)
      ek[kb][ch] = (lr + kb * 16) * 64 + ((ch * 32 + lg * 8) ^ swk);
  int ev = lr * 32 + ((lg ^ ((lr >> 1) & 3)) * 8);  // + m*512

  f32x4 oacc[4] = {};
  f32x4 dacc = {};
  const f32x4 cinit = {-C2L2, -C2L2, -C2L2, -C2L2};
  const h8 ones8 = {(f16)1.0f, (f16)1.0f, (f16)1.0f, (f16)1.0f,
                    (f16)1.0f, (f16)1.0f, (f16)1.0f, (f16)1.0f};

  // prologue: three tiles in flight (12 outstanding loads per wave)
  STAGE(0, 0);
  STAGE(1, 1);
  STAGE(2, 2);

  for (int kt = 0; kt < NT64; ++kt) {
    int cur = kt % 3;
    // wait ONLY for tile kt's 4 loads (8 of tiles kt+1,kt+2 remain in flight)
    asm volatile("s_waitcnt vmcnt(8)" ::: "memory");
    __builtin_amdgcn_sched_barrier(0);
    __builtin_amdgcn_s_barrier();  // all waves' tile-kt loads landed
    __builtin_amdgcn_sched_barrier(0);

    const f16* kb_ = kbuf[cur];
    const f16* vb_ = vbuf[cur];
#pragma unroll
    for (int sub = 0; sub < 2; ++sub) {
      int sb = sub * 2048;
      h8 kf[2][2];
#pragma unroll
      for (int kb = 0; kb < 2; ++kb)
#pragma unroll
        for (int ch = 0; ch < 2; ++ch) kf[kb][ch] = *(const h8*)&kb_[sb + ek[kb][ch]];
      h8 vv[4];
#pragma unroll
      for (int m = 0; m < 4; ++m) vv[m] = *(const h8*)&vb_[sb + ev + m * 512];

      __builtin_amdgcn_s_setprio(1);
      f32x4 sacc[2];
#pragma unroll
      for (int kb = 0; kb < 2; ++kb) {
        sacc[kb] = MFMA32(kf[kb][0], qf0, cinit);
        sacc[kb] = MFMA32(kf[kb][1], qf1, sacc[kb]);
      }
      float e0 = EXP2(sacc[0][0]);
      float e1 = EXP2(sacc[0][1]);
      float e2 = EXP2(sacc[0][2]);
      float e3 = EXP2(sacc[0][3]);
      float e4 = EXP2(sacc[1][0]);
      float e5 = EXP2(sacc[1][1]);
      float e6 = EXP2(sacc[1][2]);
      float e7 = EXP2(sacc[1][3]);
      fp16x2 p01 = __builtin_amdgcn_cvt_pkrtz(e0, e1);
      fp16x2 p23 = __builtin_amdgcn_cvt_pkrtz(e2, e3);
      fp16x2 p45 = __builtin_amdgcn_cvt_pkrtz(e4, e5);
      fp16x2 p67 = __builtin_amdgcn_cvt_pkrtz(e6, e7);
      fp16x4 lo4 = __builtin_shufflevector(p01, p23, 0, 1, 2, 3);
      fp16x4 hi4 = __builtin_shufflevector(p45, p67, 0, 1, 2, 3);
      fp16x8 p8 = __builtin_shufflevector(lo4, hi4, 0, 1, 2, 3, 4, 5, 6, 7);
      h8 pf8 = __builtin_bit_cast(h8, p8);

      dacc = MFMA32(ones8, pf8, dacc);
#pragma unroll
      for (int m = 0; m < 4; ++m) oacc[m] = MFMA32(vv[m], pf8, oacc[m]);
      __builtin_amdgcn_s_setprio(0);
    }

    __builtin_amdgcn_sched_barrier(0);
    __builtin_amdgcn_s_barrier();  // all waves done READING buf[cur]
    __builtin_amdgcn_sched_barrier(0);
    int nxt = (kt + 3) & (NT64 - 1);
    STAGE(cur, nxt);
  }

  // epilogue: res written CHUNK-SWIZZLED (chunk ch of row s at ch^(s&7))
  int b = bh >> 2, h = bh & 3;
  float inv = 1.0f / dacc[0];  // every lane holds its own q-column's sum
  int s = q0 + lr;
  f16* rrow = res + (size_t)(b * SS + s) * CC;
  int sk = s & 7;
#pragma unroll
  for (int m = 0; m < 4; ++m) {
    int d = h * 64 + m * 16 + lg * 4;
    int ch = d >> 3;
    h4 rv;
#pragma unroll
    for (int r = 0; r < 4; ++r) rv[r] = (f16)(oacc[m][r] * inv);
    *(h4*)(rrow + ((ch ^ sk) << 3) + (d & 7)) = rv;
  }
}

// ---------------- out GEMM + bias + residual (LDS-staged) ----------------
// Grid (32 s-tiles, 4 c-tiles, 8 b) = 1024 blocks, 4 waves; LDS 80KB -> 2 blocks/CU.
// Stage res-tile (swizzled rows) + wo-tile (swizzled rows) + x-tile (fp32,
// chunk-swizzled via per-lane source addresses). After MFMA (+barrier) the fp32
// out-tile Ot reuses the As region; dump is full-line coalesced.
__global__ __launch_bounds__(256) void k_out(const f16* __restrict__ res,
                                             const f16* __restrict__ wo,
                                             const float* __restrict__ bo,
                                             const float* __restrict__ x,
                                             float* __restrict__ out) {
  __shared__ f16 As[16384];   // 64 s x 256 c (32KB), swizzled rows
  __shared__ f16 Bs[16384];   // 64 c x 256 k (32KB), swizzled rows
  __shared__ float Xs[4096];  // 64 c x 64 s fp32 (16KB), chunk-swizzled
  float* Ot = (float*)As;     // 64 c x 68 s fp32 (17.4KB) after MFMA barrier

  int b = blockIdx.z;
  int c0 = blockIdx.y * 64;
  int s0 = blockIdx.x * 64;
  int w = threadIdx.x >> 6, l = threadIdx.x & 63;
  int lr = l & 15, lg = l >> 4;

  const f16* Ag = res + ((size_t)b * SS + s0) * CC;
  const f16* Bg = wo + (size_t)c0 * CC;
#pragma unroll
  for (int i = 0; i < 8; ++i) {
    int off = w * 4096 + i * 512;
    async_ld16(Ag + off + l * 8, &As[off]);
    async_ld16(Bg + off + l * 8, &Bs[off]);
  }
  // x-tile: LDS slot (c-row cl, 16B-chunk cidx) <- global chunk (cidx ^ (cl&7))
#pragma unroll
  for (int i = 0; i < 4; ++i) {
    int cl = w * 16 + i * 4 + (l >> 4);
    int cidx = l & 15;
    const float* src =
        x + ((size_t)b * CC + c0 + cl) * SS + s0 + ((cidx ^ (cl & 7)) << 2);
    async_ld16((const f16*)src, (f16*)&Xs[w * 1024 + i * 256 + l * 4]);
  }
  asm volatile("s_waitcnt vmcnt(0)" ::: "memory");
  __syncthreads();

  f32x4 acc[4] = {};
#pragma unroll
  for (int kk = 0; kk < CC; kk += 32) {
    int chs = (((kk >> 3) + lg) ^ (lr & 7)) << 3;
    h8 af = *(const h8*)&As[(w * 16 + lr) * 256 + chs];
#pragma unroll
    for (int n = 0; n < 4; ++n) {
      h8 bf = *(const h8*)&Bs[(n * 16 + lr) * 256 + chs];
      acc[n] = MFMA32(af, bf, acc[n]);
    }
  }
  __syncthreads();  // As/Bs reads complete -> Ot may overwrite As region

  // epilogue: bias + residual from Xs, repack fp32 into Ot[c][s] (pad 68)
#pragma unroll
  for (int n = 0; n < 4; ++n) {
    int c = c0 + n * 16 + lr;
    float bb = bo[c];
    float4 xv =
        *(const float4*)&Xs[(n * 16 + lr) * 64 + (((w * 4 + lg) ^ (lr & 7)) << 2)];
    float4 ov;
    ov.x = acc[n][0] + bb + xv.x;
    ov.y = acc[n][1] + bb + xv.y;
    ov.z = acc[n][2] + bb + xv.z;
    ov.w = acc[n][3] + bb + xv.w;
    *(float4*)&Ot[(n * 16 + lr) * 68 + w * 16 + lg * 4] = ov;
  }
  __syncthreads();

  // dump: 64 c-rows x 64 s fp32, full-line coalesced (64B per lane)
  int cl = threadIdx.x >> 2, sc = (threadIdx.x & 3) * 16;
  float* orow = out + ((size_t)b * CC + c0 + cl) * SS + s0 + sc;
  const float* srow = &Ot[cl * 68 + sc];
#pragma unroll
  for (int j = 0; j < 4; ++j) *(float4*)(orow + j * 4) = *(const float4*)(srow + j * 4);
}

extern "C" void kernel_launch(void* const* d_in, const int* in_sizes, int n_in,
                              void* d_out, int out_size, void* d_ws, size_t ws_size,
                              hipStream_t stream) {
  const float* x = (const float*)d_in[0];
  const float* w_proj = (const float*)d_in[1];
  const float* b_proj = (const float*)d_in[2];
  const float* w_out = (const float*)d_in[3];
  const float* b_out = (const float*)d_in[4];
  float* out = (float*)d_out;

  char* p = (char*)d_ws;
  f16* xt = (f16*)p; p += (size_t)BB * SS * CC * 2;
  f16* wp = (f16*)p; p += (size_t)O3 * CC * 2;
  f16* wo = (f16*)p; p += (size_t)CC * CC * 2;
  f16* qh = (f16*)p; p += (size_t)BB * HH * SS * DK * 2;
  f16* ksw = (f16*)p; p += (size_t)BB * HH * SS * DK * 2;
  f16* vsw = (f16*)p; p += (size_t)BB * HH * SS * DK * 2;
  f16* res = (f16*)p;

  k_prep<<<dim3(SS / 64, CC / 64, BB + 1), 256, 0, stream>>>(x, xt, w_proj, w_out, wp, wo);
  k_qkv<<<dim3(SS / 64, O3 / 64, BB), 256, 0, stream>>>(xt, wp, b_proj, qh, ksw, vsw);
  k_attn<<<dim3(1024), 256, 0, stream>>>(qh, ksw, vsw, res);
  k_out<<<dim3(SS / 64, CC / 64, BB), 256, 0, stream>>>(res, wo, b_out, x, out);
}

// Round 15
// 91.979 us; speedup vs baseline: 1.1063x; 1.1063x over previous
//
#include <hip/hip_runtime.h>

// AttentionBlock: B=8, C=256, S=2048, H=4, DK=64
// k_prep (transpose+cast x->xt [chunk-swizzled]; wp,wo chunk-swizzled casts)
// -> k_qkv (LDS-staged A/B, LDS-repacked coalesced outputs)
// -> k_attn (4 waves x 16 q, DOUBLE-buffered KV, counted vmcnt(4) + raw s_barrier;
//            res written chunk-swizzled)  [round-13 config + round-14 epilogue]
// -> k_out (LDS-staged res/wo/x, fp32 repack, full-line coalesced stores)
// fp16 storage, fp32 MFMA accum. Softmax: constant-shift exp2 (scale*log2e in Q,
// shift in MFMA C-init), raw v_exp_f32, denominator via ones-row MFMA (K=32 PV).
// Swizzle convention (rows of 256 f16 = 32 16B-chunks): chunk ch of row r stored
// at ch ^ (r&7). Same involution on write and read.

typedef _Float16 f16;
typedef __attribute__((ext_vector_type(4))) float f32x4;
typedef __attribute__((ext_vector_type(8))) _Float16 h8;
typedef __attribute__((ext_vector_type(4))) _Float16 h4;
typedef __attribute__((ext_vector_type(2))) __fp16 fp16x2;
typedef __attribute__((ext_vector_type(4))) __fp16 fp16x4;
typedef __attribute__((ext_vector_type(8))) __fp16 fp16x8;

#define SS 2048
#define CC 256
#define BB 8
#define HH 4
#define DK 64
#define O3 768
#define NT64 32  // 32 tiles of 64 keys; tile = 4096 f16 (8KB) each for K and V
#define C1F 0.1803368801111204f   // 0.125 * log2(e)
#define C2L2 11.541560327111707f  // 8 * log2(e)

#define MFMA32(a, b, c) __builtin_amdgcn_mfma_f32_16x16x32_f16(a, b, c, 0, 0, 0)

#if __has_builtin(__builtin_amdgcn_exp2f)
#define EXP2(x) __builtin_amdgcn_exp2f(x)  // raw v_exp_f32 (args in [-40,-3]: safe)
#else
#define EXP2(x) exp2f(x)
#endif

__device__ __forceinline__ void async_ld16(const f16* g, f16* lds) {
  __builtin_amdgcn_global_load_lds(
      (const __attribute__((address_space(1))) unsigned int*)g,
      (__attribute__((address_space(3))) unsigned int*)lds, 16, 0, 0);
}

// ---------------- prep ----------------
// z<8 : xt[b][s][swizzled c] = (f16) x[b][c][s]
// z==8: weight casts; wp AND wo rows chunk-swizzled
__global__ __launch_bounds__(256) void k_prep(const float* __restrict__ x,
                                              f16* __restrict__ xt,
                                              const float* __restrict__ w_proj,
                                              const float* __restrict__ w_out,
                                              f16* __restrict__ wp, f16* __restrict__ wo) {
  if (blockIdx.z == 8) {
    int slice = blockIdx.y * 32 + blockIdx.x;  // 0..127
    int i0 = slice * 2048 + threadIdx.x * 8;
    const float* src;
    f16* dst;
    if (i0 < O3 * CC) {
      src = w_proj + i0;
      int row = i0 >> 8, ch = (i0 & 255) >> 3;
      dst = wp + row * 256 + ((ch ^ (row & 7)) << 3);
    } else {
      int j = i0 - O3 * CC;
      src = w_out + j;
      int row = j >> 8, ch = (j & 255) >> 3;
      dst = wo + row * 256 + ((ch ^ (row & 7)) << 3);
    }
    float4 a = *(const float4*)src;
    float4 b = *(const float4*)(src + 4);
    h8 v = {(f16)a.x, (f16)a.y, (f16)a.z, (f16)a.w,
            (f16)b.x, (f16)b.y, (f16)b.z, (f16)b.w};
    *(h8*)dst = v;
    return;
  }
  __shared__ float tile[64][65];
  int b = blockIdx.z, c0 = blockIdx.y * 64, s0 = blockIdx.x * 64;
  int t = threadIdx.x;
#pragma unroll
  for (int it = 0; it < 16; ++it) {
    int idx = it * 256 + t;
    int cl = idx >> 6, sl = idx & 63;
    tile[cl][sl] = x[(size_t)(b * CC + c0 + cl) * SS + s0 + sl];
  }
  __syncthreads();
#pragma unroll
  for (int cid = t; cid < 512; cid += 256) {
    int sl = cid >> 3, chl = cid & 7;
    int s = s0 + sl;
    int gch = (c0 >> 3) + chl;
    h8 v;
#pragma unroll
    for (int e = 0; e < 8; ++e) v[e] = (f16)tile[chl * 8 + e][sl];
    *(h8*)(xt + (size_t)(b * SS + s) * CC + ((gch ^ (s & 7)) << 3)) = v;
  }
}

// ---------------- QKV GEMM (LDS-staged, coalesced in AND out) ----------------
__global__ __launch_bounds__(256) void k_qkv(const f16* __restrict__ xt,
                                             const f16* __restrict__ wp,
                                             const float* __restrict__ bp,
                                             f16* __restrict__ qh, f16* __restrict__ ksw,
                                             f16* __restrict__ vsw) {
  __shared__ f16 As[16384];  // 64 x 256 (32KB)
  __shared__ f16 Bs[16384];  // 64 x 256 (32KB)
  __shared__ f16 Ot[4096];   // 8KB out staging
  int b = blockIdx.z;
  int oti = blockIdx.y, o0 = oti * 64;
  int s0 = blockIdx.x * 64;
  int w = threadIdx.x >> 6, l = threadIdx.x & 63;
  int lr = l & 15, lg = l >> 4;

  const f16* Ag = xt + ((size_t)b * SS + s0) * CC;  // 32KB contiguous
  const f16* Bg = wp + (size_t)o0 * CC;
#pragma unroll
  for (int i = 0; i < 8; ++i) {
    int off = w * 4096 + i * 512;
    async_ld16(Ag + off + l * 8, &As[off]);
    async_ld16(Bg + off + l * 8, &Bs[off]);
  }
  asm volatile("s_waitcnt vmcnt(0)" ::: "memory");
  __syncthreads();

  f32x4 acc[4] = {};
#pragma unroll
  for (int kk = 0; kk < CC; kk += 32) {
    int chs = (((kk >> 3) + lg) ^ (lr & 7)) << 3;
    h8 af = *(const h8*)&As[(w * 16 + lr) * 256 + chs];
#pragma unroll
    for (int n = 0; n < 4; ++n) {
      h8 bf = *(const h8*)&Bs[(n * 16 + lr) * 256 + chs];
      acc[n] = MFMA32(af, bf, acc[n]);
    }
  }

  int seg = oti % 3;  // 0=q 1=k 2=v
  int h = oti / 3;
  int bh = b * HH + h;
  float scl = (seg == 0) ? C1F : 1.0f;
#pragma unroll
  for (int n = 0; n < 4; ++n) {
    float bb = bp[o0 + n * 16 + lr];
#pragma unroll
    for (int r = 0; r < 4; ++r) acc[n][r] = (acc[n][r] + bb) * scl;
  }

  // repack D into Ot at target layout (wave-disjoint addresses)
  if (seg == 2) {
#pragma unroll
    for (int n = 0; n < 4; ++n) {
      int d = n * 16 + lr;
#pragma unroll
      for (int r = 0; r < 4; ++r) {
        int sl = w * 16 + lg * 4 + r;
        int kl = sl & 31;
        int ps = ((kl & 15) >> 2) ^ ((d >> 1) & 3);
        Ot[(sl >> 5) * 2048 + d * 32 + ps * 8 + ((kl >> 4) << 2) + (kl & 3)] =
            (f16)acc[n][r];
      }
    }
  } else if (seg == 1) {
#pragma unroll
    for (int n = 0; n < 4; ++n) {
      int d = n * 16 + lr;
#pragma unroll
      for (int r = 0; r < 4; ++r) {
        int sl = w * 16 + lg * 4 + r;
        int kl = sl & 31;
        Ot[(sl >> 5) * 2048 + kl * 64 + (((d >> 3) ^ (kl & 7)) << 3) + (d & 7)] =
            (f16)acc[n][r];
      }
    }
  } else {
#pragma unroll
    for (int n = 0; n < 4; ++n)
#pragma unroll
      for (int r = 0; r < 4; ++r)
        Ot[(w * 16 + lg * 4 + r) * 64 + n * 16 + lr] = (f16)acc[n][r];
  }
  __syncthreads();

  int t = threadIdx.x;
  f16* dst;
  if (seg == 0)
    dst = qh + ((size_t)bh * SS + s0) * DK;
  else if (seg == 1)
    dst = ksw + ((size_t)bh * NT64 + (s0 >> 6)) * 4096;
  else
    dst = vsw + ((size_t)bh * NT64 + (s0 >> 6)) * 4096;
  *(int4*)(dst + t * 16) = *(const int4*)&Ot[t * 16];
  *(int4*)(dst + t * 16 + 8) = *(const int4*)&Ot[t * 16 + 8];
}

// ---------------- attention: 4 waves x 16 q, DOUBLE-buffered (round-13 config) ----
// 1024 blocks; 32KB LDS -> 4 blocks/CU = 16 waves/CU = 4/SIMD. Per wave per tile:
// 4 loads. Prologue stages tiles 0,1. Loop t: vmcnt(4) (tile t's 4 retired; t+1's
// 4 in flight) -> s_barrier -> compute buf[t&1] -> s_barrier -> STAGE(t&1, t+2).
__global__ __launch_bounds__(256) void k_attn(const f16* __restrict__ qh,
                                              const f16* __restrict__ ksw,
                                              const f16* __restrict__ vsw,
                                              f16* __restrict__ res) {
  __shared__ f16 kbuf[2][4096];
  __shared__ f16 vbuf[2][4096];
  int id = blockIdx.x;
  int xcd = id & 7, slot = id >> 3;  // 128 slots per XCD
  int bh = xcd * 4 + (slot >> 5);    // 4 heads per XCD -> K/V L2-resident
  int qt = slot & 31;
  int w = threadIdx.x >> 6, l = threadIdx.x & 63;
  int q0 = qt * 64 + w * 16;
  int lr = l & 15, lg = l >> 4;

  const f16* qp = qh + (size_t)(bh * SS + q0 + lr) * DK;
  h8 qf0 = *(const h8*)(qp + lg * 8);
  h8 qf1 = *(const h8*)(qp + 32 + lg * 8);

  const f16* kg = ksw + (size_t)bh * (SS * DK);
  const f16* vg = vsw + (size_t)bh * (SS * DK);

  // per-wave quarter of each 8KB buffer: 2 K-loads + 2 V-loads (16B/lane)
#define STAGE(bufi, tile)                                           \
  {                                                                 \
    const f16* kq = kg + (size_t)(tile) * 4096 + w * 1024 + l * 8;  \
    const f16* vq = vg + (size_t)(tile) * 4096 + w * 1024 + l * 8;  \
    f16* kd = &kbuf[bufi][w * 1024];                                \
    f16* vd = &vbuf[bufi][w * 1024];                                \
    async_ld16(kq, kd);                                             \
    async_ld16(kq + 512, kd + 512);                                 \
    async_ld16(vq, vd);                                             \
    async_ld16(vq + 512, vd + 512);                                 \
  }

  int swk = (lr & 7) << 3;
  int ek[2][2];
#pragma unroll
  for (int kb = 0; kb < 2; ++kb)
#pragma unroll
    for (int ch = 0; ch < 2; ++ch)
      ek[kb][ch] = (lr + kb * 16) * 64 + ((ch * 32 + lg * 8) ^ swk);
  int ev = lr * 32 + ((lg ^ ((lr >> 1) & 3)) * 8);  // + m*512

  f32x4 oacc[4] = {};
  f32x4 dacc = {};
  const f32x4 cinit = {-C2L2, -C2L2, -C2L2, -C2L2};
  const h8 ones8 = {(f16)1.0f, (f16)1.0f, (f16)1.0f, (f16)1.0f,
                    (f16)1.0f, (f16)1.0f, (f16)1.0f, (f16)1.0f};

  // prologue: two tiles in flight (8 outstanding loads per wave)
  STAGE(0, 0);
  STAGE(1, 1);

  for (int kt = 0; kt < NT64; ++kt) {
    int cur = kt & 1;
    // wait ONLY for tile kt's 4 loads (4 of tile kt+1 remain in flight)
    asm volatile("s_waitcnt vmcnt(4)" ::: "memory");
    __builtin_amdgcn_sched_barrier(0);
    __builtin_amdgcn_s_barrier();  // all waves' tile-kt loads landed
    __builtin_amdgcn_sched_barrier(0);

    const f16* kb_ = kbuf[cur];
    const f16* vb_ = vbuf[cur];
#pragma unroll
    for (int sub = 0; sub < 2; ++sub) {
      int sb = sub * 2048;
      h8 kf[2][2];
#pragma unroll
      for (int kb = 0; kb < 2; ++kb)
#pragma unroll
        for (int ch = 0; ch < 2; ++ch) kf[kb][ch] = *(const h8*)&kb_[sb + ek[kb][ch]];
      h8 vv[4];
#pragma unroll
      for (int m = 0; m < 4; ++m) vv[m] = *(const h8*)&vb_[sb + ev + m * 512];

      __builtin_amdgcn_s_setprio(1);
      f32x4 sacc[2];
#pragma unroll
      for (int kb = 0; kb < 2; ++kb) {
        sacc[kb] = MFMA32(kf[kb][0], qf0, cinit);
        sacc[kb] = MFMA32(kf[kb][1], qf1, sacc[kb]);
      }
      float e0 = EXP2(sacc[0][0]);
      float e1 = EXP2(sacc[0][1]);
      float e2 = EXP2(sacc[0][2]);
      float e3 = EXP2(sacc[0][3]);
      float e4 = EXP2(sacc[1][0]);
      float e5 = EXP2(sacc[1][1]);
      float e6 = EXP2(sacc[1][2]);
      float e7 = EXP2(sacc[1][3]);
      fp16x2 p01 = __builtin_amdgcn_cvt_pkrtz(e0, e1);
      fp16x2 p23 = __builtin_amdgcn_cvt_pkrtz(e2, e3);
      fp16x2 p45 = __builtin_amdgcn_cvt_pkrtz(e4, e5);
      fp16x2 p67 = __builtin_amdgcn_cvt_pkrtz(e6, e7);
      fp16x4 lo4 = __builtin_shufflevector(p01, p23, 0, 1, 2, 3);
      fp16x4 hi4 = __builtin_shufflevector(p45, p67, 0, 1, 2, 3);
      fp16x8 p8 = __builtin_shufflevector(lo4, hi4, 0, 1, 2, 3, 4, 5, 6, 7);
      h8 pf8 = __builtin_bit_cast(h8, p8);

      dacc = MFMA32(ones8, pf8, dacc);
#pragma unroll
      for (int m = 0; m < 4; ++m) oacc[m] = MFMA32(vv[m], pf8, oacc[m]);
      __builtin_amdgcn_s_setprio(0);
    }

    __builtin_amdgcn_sched_barrier(0);
    __builtin_amdgcn_s_barrier();  // all waves done READING buf[cur]
    __builtin_amdgcn_sched_barrier(0);
    // refill the buffer just freed; loads land any time before iter kt+2's wait
    int nxt = (kt + 2) & (NT64 - 1);
    STAGE(cur, nxt);
  }

  // epilogue: res written CHUNK-SWIZZLED (chunk ch of row s at ch^(s&7))
  int b = bh >> 2, h = bh & 3;
  float inv = 1.0f / dacc[0];  // every lane holds its own q-column's sum
  int s = q0 + lr;
  f16* rrow = res + (size_t)(b * SS + s) * CC;
  int sk = s & 7;
#pragma unroll
  for (int m = 0; m < 4; ++m) {
    int d = h * 64 + m * 16 + lg * 4;
    int ch = d >> 3;
    h4 rv;
#pragma unroll
    for (int r = 0; r < 4; ++r) rv[r] = (f16)(oacc[m][r] * inv);
    *(h4*)(rrow + ((ch ^ sk) << 3) + (d & 7)) = rv;
  }
}

// ---------------- out GEMM + bias + residual (LDS-staged) ----------------
// Grid (32 s-tiles, 4 c-tiles, 8 b) = 1024 blocks, 4 waves; LDS 80KB -> 2 blocks/CU.
// Stage res-tile (swizzled rows) + wo-tile (swizzled rows) + x-tile (fp32,
// chunk-swizzled via per-lane source addresses). After MFMA (+barrier) the fp32
// out-tile Ot reuses the As region; dump is full-line coalesced.
__global__ __launch_bounds__(256) void k_out(const f16* __restrict__ res,
                                             const f16* __restrict__ wo,
                                             const float* __restrict__ bo,
                                             const float* __restrict__ x,
                                             float* __restrict__ out) {
  __shared__ f16 As[16384];   // 64 s x 256 c (32KB), swizzled rows
  __shared__ f16 Bs[16384];   // 64 c x 256 k (32KB), swizzled rows
  __shared__ float Xs[4096];  // 64 c x 64 s fp32 (16KB), chunk-swizzled
  float* Ot = (float*)As;     // 64 c x 68 s fp32 (17.4KB) after MFMA barrier

  int b = blockIdx.z;
  int c0 = blockIdx.y * 64;
  int s0 = blockIdx.x * 64;
  int w = threadIdx.x >> 6, l = threadIdx.x & 63;
  int lr = l & 15, lg = l >> 4;

  const f16* Ag = res + ((size_t)b * SS + s0) * CC;
  const f16* Bg = wo + (size_t)c0 * CC;
#pragma unroll
  for (int i = 0; i < 8; ++i) {
    int off = w * 4096 + i * 512;
    async_ld16(Ag + off + l * 8, &As[off]);
    async_ld16(Bg + off + l * 8, &Bs[off]);
  }
  // x-tile: LDS slot (c-row cl, 16B-chunk cidx) <- global chunk (cidx ^ (cl&7))
#pragma unroll
  for (int i = 0; i < 4; ++i) {
    int cl = w * 16 + i * 4 + (l >> 4);
    int cidx = l & 15;
    const float* src =
        x + ((size_t)b * CC + c0 + cl) * SS + s0 + ((cidx ^ (cl & 7)) << 2);
    async_ld16((const f16*)src, (f16*)&Xs[w * 1024 + i * 256 + l * 4]);
  }
  asm volatile("s_waitcnt vmcnt(0)" ::: "memory");
  __syncthreads();

  f32x4 acc[4] = {};
#pragma unroll
  for (int kk = 0; kk < CC; kk += 32) {
    int chs = (((kk >> 3) + lg) ^ (lr & 7)) << 3;
    h8 af = *(const h8*)&As[(w * 16 + lr) * 256 + chs];
#pragma unroll
    for (int n = 0; n < 4; ++n) {
      h8 bf = *(const h8*)&Bs[(n * 16 + lr) * 256 + chs];
      acc[n] = MFMA32(af, bf, acc[n]);
    }
  }
  __syncthreads();  // As/Bs reads complete -> Ot may overwrite As region

  // epilogue: bias + residual from Xs, repack fp32 into Ot[c][s] (pad 68)
#pragma unroll
  for (int n = 0; n < 4; ++n) {
    int c = c0 + n * 16 + lr;
    float bb = bo[c];
    float4 xv =
        *(const float4*)&Xs[(n * 16 + lr) * 64 + (((w * 4 + lg) ^ (lr & 7)) << 2)];
    float4 ov;
    ov.x = acc[n][0] + bb + xv.x;
    ov.y = acc[n][1] + bb + xv.y;
    ov.z = acc[n][2] + bb + xv.z;
    ov.w = acc[n][3] + bb + xv.w;
    *(float4*)&Ot[(n * 16 + lr) * 68 + w * 16 + lg * 4] = ov;
  }
  __syncthreads();

  // dump: 64 c-rows x 64 s fp32, full-line coalesced (64B per lane)
  int cl = threadIdx.x >> 2, sc = (threadIdx.x & 3) * 16;
  float* orow = out + ((size_t)b * CC + c0 + cl) * SS + s0 + sc;
  const float* srow = &Ot[cl * 68 + sc];
#pragma unroll
  for (int j = 0; j < 4; ++j) *(float4*)(orow + j * 4) = *(const float4*)(srow + j * 4);
}

extern "C" void kernel_launch(void* const* d_in, const int* in_sizes, int n_in,
                              void* d_out, int out_size, void* d_ws, size_t ws_size,
                              hipStream_t stream) {
  const float* x = (const float*)d_in[0];
  const float* w_proj = (const float*)d_in[1];
  const float* b_proj = (const float*)d_in[2];
  const float* w_out = (const float*)d_in[3];
  const float* b_out = (const float*)d_in[4];
  float* out = (float*)d_out;

  char* p = (char*)d_ws;
  f16* xt = (f16*)p; p += (size_t)BB * SS * CC * 2;
  f16* wp = (f16*)p; p += (size_t)O3 * CC * 2;
  f16* wo = (f16*)p; p += (size_t)CC * CC * 2;
  f16* qh = (f16*)p; p += (size_t)BB * HH * SS * DK * 2;
  f16* ksw = (f16*)p; p += (size_t)BB * HH * SS * DK * 2;
  f16* vsw = (f16*)p; p += (size_t)BB * HH * SS * DK * 2;
  f16* res = (f16*)p;

  k_prep<<<dim3(SS / 64, CC / 64, BB + 1), 256, 0, stream>>>(x, xt, w_proj, w_out, wp, wo);
  k_qkv<<<dim3(SS / 64, O3 / 64, BB), 256, 0, stream>>>(xt, wp, b_proj, qh, ksw, vsw);
  k_attn<<<dim3(1024), 256, 0, stream>>>(qh, ksw, vsw, res);
  k_out<<<dim3(SS / 64, CC / 64, BB), 256, 0, stream>>>(res, wo, b_out, x, out);
}

// Round 16
// 85.536 us; speedup vs baseline: 1.1896x; 1.0753x over previous
//
#include <hip/hip_runtime.h>

// AttentionBlock: B=8, C=256, S=2048, H=4, DK=64
// k_prep (transpose+cast x->xt [chunk-swizzled]; wp,wo chunk-swizzled casts)
// -> k_qkv (LDS-staged A/B, LDS-repacked coalesced outputs)
// -> k_attn (KEY-SPLIT 4 waves: 2 q-groups x 2 key-groups; each wave reads only
//            its 8KB half of the KV tile -> per-CU LDS read traffic halved.
//            Double-buffered, counted vmcnt(4) + raw s_barrier; cross-wave
//            O/denom reduction in epilogue; res written chunk-swizzled)
// -> k_out (LDS-staged res/wo/x, fp32 repack, full-line coalesced stores)
// fp16 storage, fp32 MFMA accum. Softmax: constant-shift exp2 (scale*log2e in Q,
// shift in MFMA C-init), raw v_exp_f32, denominator via ones-row MFMA (K=32 PV).
// Key-split is exact under constant-shift softmax: partial denoms/O just add.
// Swizzle convention (rows of 256 f16 = 32 16B-chunks): chunk ch of row r stored
// at ch ^ (r&7). Same involution on write and read.

typedef _Float16 f16;
typedef __attribute__((ext_vector_type(4))) float f32x4;
typedef __attribute__((ext_vector_type(8))) _Float16 h8;
typedef __attribute__((ext_vector_type(4))) _Float16 h4;
typedef __attribute__((ext_vector_type(2))) __fp16 fp16x2;
typedef __attribute__((ext_vector_type(4))) __fp16 fp16x4;
typedef __attribute__((ext_vector_type(8))) __fp16 fp16x8;

#define SS 2048
#define CC 256
#define BB 8
#define HH 4
#define DK 64
#define O3 768
#define NT64 32  // 32 tiles of 64 keys; tile = 4096 f16 (8KB) each for K and V
#define C1F 0.1803368801111204f   // 0.125 * log2(e)
#define C2L2 11.541560327111707f  // 8 * log2(e)

#define MFMA32(a, b, c) __builtin_amdgcn_mfma_f32_16x16x32_f16(a, b, c, 0, 0, 0)

#if __has_builtin(__builtin_amdgcn_exp2f)
#define EXP2(x) __builtin_amdgcn_exp2f(x)  // raw v_exp_f32 (args in [-40,-3]: safe)
#else
#define EXP2(x) exp2f(x)
#endif

__device__ __forceinline__ void async_ld16(const f16* g, f16* lds) {
  __builtin_amdgcn_global_load_lds(
      (const __attribute__((address_space(1))) unsigned int*)g,
      (__attribute__((address_space(3))) unsigned int*)lds, 16, 0, 0);
}

// ---------------- prep ----------------
// z<8 : xt[b][s][swizzled c] = (f16) x[b][c][s]
// z==8: weight casts; wp AND wo rows chunk-swizzled
__global__ __launch_bounds__(256) void k_prep(const float* __restrict__ x,
                                              f16* __restrict__ xt,
                                              const float* __restrict__ w_proj,
                                              const float* __restrict__ w_out,
                                              f16* __restrict__ wp, f16* __restrict__ wo) {
  if (blockIdx.z == 8) {
    int slice = blockIdx.y * 32 + blockIdx.x;  // 0..127
    int i0 = slice * 2048 + threadIdx.x * 8;
    const float* src;
    f16* dst;
    if (i0 < O3 * CC) {
      src = w_proj + i0;
      int row = i0 >> 8, ch = (i0 & 255) >> 3;
      dst = wp + row * 256 + ((ch ^ (row & 7)) << 3);
    } else {
      int j = i0 - O3 * CC;
      src = w_out + j;
      int row = j >> 8, ch = (j & 255) >> 3;
      dst = wo + row * 256 + ((ch ^ (row & 7)) << 3);
    }
    float4 a = *(const float4*)src;
    float4 b = *(const float4*)(src + 4);
    h8 v = {(f16)a.x, (f16)a.y, (f16)a.z, (f16)a.w,
            (f16)b.x, (f16)b.y, (f16)b.z, (f16)b.w};
    *(h8*)dst = v;
    return;
  }
  __shared__ float tile[64][65];
  int b = blockIdx.z, c0 = blockIdx.y * 64, s0 = blockIdx.x * 64;
  int t = threadIdx.x;
#pragma unroll
  for (int it = 0; it < 16; ++it) {
    int idx = it * 256 + t;
    int cl = idx >> 6, sl = idx & 63;
    tile[cl][sl] = x[(size_t)(b * CC + c0 + cl) * SS + s0 + sl];
  }
  __syncthreads();
#pragma unroll
  for (int cid = t; cid < 512; cid += 256) {
    int sl = cid >> 3, chl = cid & 7;
    int s = s0 + sl;
    int gch = (c0 >> 3) + chl;
    h8 v;
#pragma unroll
    for (int e = 0; e < 8; ++e) v[e] = (f16)tile[chl * 8 + e][sl];
    *(h8*)(xt + (size_t)(b * SS + s) * CC + ((gch ^ (s & 7)) << 3)) = v;
  }
}

// ---------------- QKV GEMM (LDS-staged, coalesced in AND out) ----------------
__global__ __launch_bounds__(256) void k_qkv(const f16* __restrict__ xt,
                                             const f16* __restrict__ wp,
                                             const float* __restrict__ bp,
                                             f16* __restrict__ qh, f16* __restrict__ ksw,
                                             f16* __restrict__ vsw) {
  __shared__ f16 As[16384];  // 64 x 256 (32KB)
  __shared__ f16 Bs[16384];  // 64 x 256 (32KB)
  __shared__ f16 Ot[4096];   // 8KB out staging
  int b = blockIdx.z;
  int oti = blockIdx.y, o0 = oti * 64;
  int s0 = blockIdx.x * 64;
  int w = threadIdx.x >> 6, l = threadIdx.x & 63;
  int lr = l & 15, lg = l >> 4;

  const f16* Ag = xt + ((size_t)b * SS + s0) * CC;  // 32KB contiguous
  const f16* Bg = wp + (size_t)o0 * CC;
#pragma unroll
  for (int i = 0; i < 8; ++i) {
    int off = w * 4096 + i * 512;
    async_ld16(Ag + off + l * 8, &As[off]);
    async_ld16(Bg + off + l * 8, &Bs[off]);
  }
  asm volatile("s_waitcnt vmcnt(0)" ::: "memory");
  __syncthreads();

  f32x4 acc[4] = {};
#pragma unroll
  for (int kk = 0; kk < CC; kk += 32) {
    int chs = (((kk >> 3) + lg) ^ (lr & 7)) << 3;
    h8 af = *(const h8*)&As[(w * 16 + lr) * 256 + chs];
#pragma unroll
    for (int n = 0; n < 4; ++n) {
      h8 bf = *(const h8*)&Bs[(n * 16 + lr) * 256 + chs];
      acc[n] = MFMA32(af, bf, acc[n]);
    }
  }

  int seg = oti % 3;  // 0=q 1=k 2=v
  int h = oti / 3;
  int bh = b * HH + h;
  float scl = (seg == 0) ? C1F : 1.0f;
#pragma unroll
  for (int n = 0; n < 4; ++n) {
    float bb = bp[o0 + n * 16 + lr];
#pragma unroll
    for (int r = 0; r < 4; ++r) acc[n][r] = (acc[n][r] + bb) * scl;
  }

  // repack D into Ot at target layout (wave-disjoint addresses)
  if (seg == 2) {
#pragma unroll
    for (int n = 0; n < 4; ++n) {
      int d = n * 16 + lr;
#pragma unroll
      for (int r = 0; r < 4; ++r) {
        int sl = w * 16 + lg * 4 + r;
        int kl = sl & 31;
        int ps = ((kl & 15) >> 2) ^ ((d >> 1) & 3);
        Ot[(sl >> 5) * 2048 + d * 32 + ps * 8 + ((kl >> 4) << 2) + (kl & 3)] =
            (f16)acc[n][r];
      }
    }
  } else if (seg == 1) {
#pragma unroll
    for (int n = 0; n < 4; ++n) {
      int d = n * 16 + lr;
#pragma unroll
      for (int r = 0; r < 4; ++r) {
        int sl = w * 16 + lg * 4 + r;
        int kl = sl & 31;
        Ot[(sl >> 5) * 2048 + kl * 64 + (((d >> 3) ^ (kl & 7)) << 3) + (d & 7)] =
            (f16)acc[n][r];
      }
    }
  } else {
#pragma unroll
    for (int n = 0; n < 4; ++n)
#pragma unroll
      for (int r = 0; r < 4; ++r)
        Ot[(w * 16 + lg * 4 + r) * 64 + n * 16 + lr] = (f16)acc[n][r];
  }
  __syncthreads();

  int t = threadIdx.x;
  f16* dst;
  if (seg == 0)
    dst = qh + ((size_t)bh * SS + s0) * DK;
  else if (seg == 1)
    dst = ksw + ((size_t)bh * NT64 + (s0 >> 6)) * 4096;
  else
    dst = vsw + ((size_t)bh * NT64 + (s0 >> 6)) * 4096;
  *(int4*)(dst + t * 16) = *(const int4*)&Ot[t * 16];
  *(int4*)(dst + t * 16 + 8) = *(const int4*)&Ot[t * 16 + 8];
}

// ---------------- attention: KEY-SPLIT 2 q-groups x 2 key-groups ----------------
// 1024 blocks; 32KB LDS; ~110 VGPR forced <=128 -> 4 blocks/CU = 16 waves/CU.
// Wave w: qg=w&1 owns 32 queries (2 subgroups of 16), kg=w>>1 owns key-subtile kg
// (32 of 64 keys). Each wave reads ONLY its 4KB K + 4KB V half per tile -> per-CU
// LDS reads halved vs all-waves-read-all. Partial O / denom summed across the two
// kg waves in the epilogue (exact for constant-shift softmax).
__global__ __launch_bounds__(256, 4) void k_attn(const f16* __restrict__ qh,
                                                 const f16* __restrict__ ksw,
                                                 const f16* __restrict__ vsw,
                                                 f16* __restrict__ res) {
  __shared__ f16 kbuf[2][4096];
  __shared__ f16 vbuf[2][4096];
  int id = blockIdx.x;
  int xcd = id & 7, slot = id >> 3;  // 128 slots per XCD
  int bh = xcd * 4 + (slot >> 5);    // 4 heads per XCD -> K/V L2-resident
  int qt = slot & 31;
  int w = threadIdx.x >> 6, l = threadIdx.x & 63;
  int qg = w & 1, kg = w >> 1;
  int q0w = qt * 64 + qg * 32;
  int lr = l & 15, lg = l >> 4;

  h8 qf[2][2];
#pragma unroll
  for (int qs = 0; qs < 2; ++qs) {
    const f16* qp = qh + (size_t)(bh * SS + q0w + qs * 16 + lr) * DK;
    qf[qs][0] = *(const h8*)(qp + lg * 8);
    qf[qs][1] = *(const h8*)(qp + 32 + lg * 8);
  }

  const f16* kg_ = ksw + (size_t)bh * (SS * DK);
  const f16* vg_ = vsw + (size_t)bh * (SS * DK);

  // all 4 waves cooperatively stage the full 8KB K + 8KB V tile (quarter each)
#define STAGE(bufi, tile)                                            \
  {                                                                  \
    const f16* kq = kg_ + (size_t)(tile) * 4096 + w * 1024 + l * 8;  \
    const f16* vq = vg_ + (size_t)(tile) * 4096 + w * 1024 + l * 8;  \
    f16* kd = &kbuf[bufi][w * 1024];                                 \
    f16* vd = &vbuf[bufi][w * 1024];                                 \
    async_ld16(kq, kd);                                              \
    async_ld16(kq + 512, kd + 512);                                  \
    async_ld16(vq, vd);                                              \
    async_ld16(vq + 512, vd + 512);                                  \
  }

  int swk = (lr & 7) << 3;
  int ek[2][2];
#pragma unroll
  for (int kb = 0; kb < 2; ++kb)
#pragma unroll
    for (int ch = 0; ch < 2; ++ch)
      ek[kb][ch] = (lr + kb * 16) * 64 + ((ch * 32 + lg * 8) ^ swk);
  int ev = lr * 32 + ((lg ^ ((lr >> 1) & 3)) * 8);  // + m*512

  f32x4 oacc[2][4] = {};
  f32x4 dacc[2] = {};
  const f32x4 cinit = {-C2L2, -C2L2, -C2L2, -C2L2};
  const h8 ones8 = {(f16)1.0f, (f16)1.0f, (f16)1.0f, (f16)1.0f,
                    (f16)1.0f, (f16)1.0f, (f16)1.0f, (f16)1.0f};

  int sb = kg * 2048;  // this wave's key-subtile base

  STAGE(0, 0);
  STAGE(1, 1);

  for (int kt = 0; kt < NT64; ++kt) {
    int cur = kt & 1;
    asm volatile("s_waitcnt vmcnt(4)" ::: "memory");
    __builtin_amdgcn_sched_barrier(0);
    __builtin_amdgcn_s_barrier();  // all waves' tile-kt loads landed
    __builtin_amdgcn_sched_barrier(0);

    const f16* kb_ = &kbuf[cur][sb];
    const f16* vb_ = &vbuf[cur][sb];
    h8 kf[2][2];
#pragma unroll
    for (int kb = 0; kb < 2; ++kb)
#pragma unroll
      for (int ch = 0; ch < 2; ++ch) kf[kb][ch] = *(const h8*)&kb_[ek[kb][ch]];
    h8 vv[4];
#pragma unroll
    for (int m = 0; m < 4; ++m) vv[m] = *(const h8*)&vb_[ev + m * 512];

    __builtin_amdgcn_s_setprio(1);
    f32x4 sacc[2][2];
#pragma unroll
    for (int qs = 0; qs < 2; ++qs)
#pragma unroll
      for (int kb = 0; kb < 2; ++kb) {
        sacc[qs][kb] = MFMA32(kf[kb][0], qf[qs][0], cinit);
        sacc[qs][kb] = MFMA32(kf[kb][1], qf[qs][1], sacc[qs][kb]);
      }
    h8 pf8[2];
#pragma unroll
    for (int qs = 0; qs < 2; ++qs) {
      float e0 = EXP2(sacc[qs][0][0]);
      float e1 = EXP2(sacc[qs][0][1]);
      float e2 = EXP2(sacc[qs][0][2]);
      float e3 = EXP2(sacc[qs][0][3]);
      float e4 = EXP2(sacc[qs][1][0]);
      float e5 = EXP2(sacc[qs][1][1]);
      float e6 = EXP2(sacc[qs][1][2]);
      float e7 = EXP2(sacc[qs][1][3]);
      fp16x2 p01 = __builtin_amdgcn_cvt_pkrtz(e0, e1);
      fp16x2 p23 = __builtin_amdgcn_cvt_pkrtz(e2, e3);
      fp16x2 p45 = __builtin_amdgcn_cvt_pkrtz(e4, e5);
      fp16x2 p67 = __builtin_amdgcn_cvt_pkrtz(e6, e7);
      fp16x4 lo4 = __builtin_shufflevector(p01, p23, 0, 1, 2, 3);
      fp16x4 hi4 = __builtin_shufflevector(p45, p67, 0, 1, 2, 3);
      fp16x8 p8 = __builtin_shufflevector(lo4, hi4, 0, 1, 2, 3, 4, 5, 6, 7);
      pf8[qs] = __builtin_bit_cast(h8, p8);
    }
#pragma unroll
    for (int qs = 0; qs < 2; ++qs) dacc[qs] = MFMA32(ones8, pf8[qs], dacc[qs]);
#pragma unroll
    for (int qs = 0; qs < 2; ++qs)
#pragma unroll
      for (int m = 0; m < 4; ++m) oacc[qs][m] = MFMA32(vv[m], pf8[qs], oacc[qs][m]);
    __builtin_amdgcn_s_setprio(0);

    __builtin_amdgcn_sched_barrier(0);
    __builtin_amdgcn_s_barrier();  // all waves done READING buf[cur]
    __builtin_amdgcn_sched_barrier(0);
    int nxt = (kt + 2) & (NT64 - 1);
    STAGE(cur, nxt);
  }

  // drain outstanding stages before reusing kbuf/vbuf for the reduction
  asm volatile("s_waitcnt vmcnt(0)" ::: "memory");
  __syncthreads();

  float* red = (float*)&kbuf[0][0];   // 16 KB: 2 qg x (2 qs x 4 m) x 256 floats
  float* redd = (float*)&vbuf[0][0];  // 1 KB: 4 x 64 floats
  if (kg == 1) {
#pragma unroll
    for (int qs = 0; qs < 2; ++qs) {
#pragma unroll
      for (int m = 0; m < 4; ++m)
        *(f32x4*)&red[(qg * 8 + qs * 4 + m) * 256 + l * 4] = oacc[qs][m];
      redd[(qg * 2 + qs) * 64 + l] = dacc[qs][0];
    }
  }
  __syncthreads();
  if (kg == 0) {
    int b = bh >> 2, h = bh & 3;
#pragma unroll
    for (int qs = 0; qs < 2; ++qs) {
      float inv = 1.0f / (dacc[qs][0] + redd[(qg * 2 + qs) * 64 + l]);
      int s = q0w + qs * 16 + lr;
      f16* rrow = res + (size_t)(b * SS + s) * CC;
      int sk = s & 7;
#pragma unroll
      for (int m = 0; m < 4; ++m) {
        f32x4 o2 = *(const f32x4*)&red[(qg * 8 + qs * 4 + m) * 256 + l * 4];
        int d = h * 64 + m * 16 + lg * 4;
        int ch = d >> 3;
        h4 rv;
#pragma unroll
        for (int r = 0; r < 4; ++r) rv[r] = (f16)((oacc[qs][m][r] + o2[r]) * inv);
        *(h4*)(rrow + ((ch ^ sk) << 3) + (d & 7)) = rv;
      }
    }
  }
}

// ---------------- out GEMM + bias + residual (LDS-staged) ----------------
__global__ __launch_bounds__(256) void k_out(const f16* __restrict__ res,
                                             const f16* __restrict__ wo,
                                             const float* __restrict__ bo,
                                             const float* __restrict__ x,
                                             float* __restrict__ out) {
  __shared__ f16 As[16384];   // 64 s x 256 c (32KB), swizzled rows
  __shared__ f16 Bs[16384];   // 64 c x 256 k (32KB), swizzled rows
  __shared__ float Xs[4096];  // 64 c x 64 s fp32 (16KB), chunk-swizzled
  float* Ot = (float*)As;     // 64 c x 68 s fp32 (17.4KB) after MFMA barrier

  int b = blockIdx.z;
  int c0 = blockIdx.y * 64;
  int s0 = blockIdx.x * 64;
  int w = threadIdx.x >> 6, l = threadIdx.x & 63;
  int lr = l & 15, lg = l >> 4;

  const f16* Ag = res + ((size_t)b * SS + s0) * CC;
  const f16* Bg = wo + (size_t)c0 * CC;
#pragma unroll
  for (int i = 0; i < 8; ++i) {
    int off = w * 4096 + i * 512;
    async_ld16(Ag + off + l * 8, &As[off]);
    async_ld16(Bg + off + l * 8, &Bs[off]);
  }
  // x-tile: LDS slot (c-row cl, 16B-chunk cidx) <- global chunk (cidx ^ (cl&7))
#pragma unroll
  for (int i = 0; i < 4; ++i) {
    int cl = w * 16 + i * 4 + (l >> 4);
    int cidx = l & 15;
    const float* src =
        x + ((size_t)b * CC + c0 + cl) * SS + s0 + ((cidx ^ (cl & 7)) << 2);
    async_ld16((const f16*)src, (f16*)&Xs[w * 1024 + i * 256 + l * 4]);
  }
  asm volatile("s_waitcnt vmcnt(0)" ::: "memory");
  __syncthreads();

  f32x4 acc[4] = {};
#pragma unroll
  for (int kk = 0; kk < CC; kk += 32) {
    int chs = (((kk >> 3) + lg) ^ (lr & 7)) << 3;
    h8 af = *(const h8*)&As[(w * 16 + lr) * 256 + chs];
#pragma unroll
    for (int n = 0; n < 4; ++n) {
      h8 bf = *(const h8*)&Bs[(n * 16 + lr) * 256 + chs];
      acc[n] = MFMA32(af, bf, acc[n]);
    }
  }
  __syncthreads();  // As/Bs reads complete -> Ot may overwrite As region

  // epilogue: bias + residual from Xs, repack fp32 into Ot[c][s] (pad 68)
#pragma unroll
  for (int n = 0; n < 4; ++n) {
    int c = c0 + n * 16 + lr;
    float bb = bo[c];
    float4 xv =
        *(const float4*)&Xs[(n * 16 + lr) * 64 + (((w * 4 + lg) ^ (lr & 7)) << 2)];
    float4 ov;
    ov.x = acc[n][0] + bb + xv.x;
    ov.y = acc[n][1] + bb + xv.y;
    ov.z = acc[n][2] + bb + xv.z;
    ov.w = acc[n][3] + bb + xv.w;
    *(float4*)&Ot[(n * 16 + lr) * 68 + w * 16 + lg * 4] = ov;
  }
  __syncthreads();

  // dump: 64 c-rows x 64 s fp32, full-line coalesced (64B per lane)
  int cl = threadIdx.x >> 2, sc = (threadIdx.x & 3) * 16;
  float* orow = out + ((size_t)b * CC + c0 + cl) * SS + s0 + sc;
  const float* srow = &Ot[cl * 68 + sc];
#pragma unroll
  for (int j = 0; j < 4; ++j) *(float4*)(orow + j * 4) = *(const float4*)(srow + j * 4);
}

extern "C" void kernel_launch(void* const* d_in, const int* in_sizes, int n_in,
                              void* d_out, int out_size, void* d_ws, size_t ws_size,
                              hipStream_t stream) {
  const float* x = (const float*)d_in[0];
  const float* w_proj = (const float*)d_in[1];
  const float* b_proj = (const float*)d_in[2];
  const float* w_out = (const float*)d_in[3];
  const float* b_out = (const float*)d_in[4];
  float* out = (float*)d_out;

  char* p = (char*)d_ws;
  f16* xt = (f16*)p; p += (size_t)BB * SS * CC * 2;
  f16* wp = (f16*)p; p += (size_t)O3 * CC * 2;
  f16* wo = (f16*)p; p += (size_t)CC * CC * 2;
  f16* qh = (f16*)p; p += (size_t)BB * HH * SS * DK * 2;
  f16* ksw = (f16*)p; p += (size_t)BB * HH * SS * DK * 2;
  f16* vsw = (f16*)p; p += (size_t)BB * HH * SS * DK * 2;
  f16* res = (f16*)p;

  k_prep<<<dim3(SS / 64, CC / 64, BB + 1), 256, 0, stream>>>(x, xt, w_proj, w_out, wp, wo);
  k_qkv<<<dim3(SS / 64, O3 / 64, BB), 256, 0, stream>>>(xt, wp, b_proj, qh, ksw, vsw);
  k_attn<<<dim3(1024), 256, 0, stream>>>(qh, ksw, vsw, res);
  k_out<<<dim3(SS / 64, CC / 64, BB), 256, 0, stream>>>(res, wo, b_out, x, out);
}